// Round 1
// baseline (1690.153 us; speedup 1.0000x reference)
//
#include <hip/hip_runtime.h>
#include <hip/hip_bf16.h>
#include <math.h>

#define T_TOK 4096
#define DIM   1024
#define HDIM  256
#define N_SH  2
#define N_RT  32
#define TOPK  4
#define TB    64          // tokens per expert tile
#define LDP   (TB + 4)    // LDS row stride (keeps 16B alignment, breaks worst conflicts)

__device__ __forceinline__ float gelu_exact(float v) {
    return 0.5f * v * (1.0f + erff(v * 0.70710678118654752440f));
}

// ---------------- Kernel A: RMSNorm + router softmax + top-4 scatter ----------------
__global__ __launch_bounds__(256) void rms_router_kernel(
    const float* __restrict__ x, const float* __restrict__ rms_w,
    const float* __restrict__ cent,
    float* __restrict__ xn, float* __restrict__ y, float* __restrict__ aff_out,
    int* __restrict__ counts, int* __restrict__ lists, float* __restrict__ lscores)
{
    const int t   = blockIdx.x;
    const int tid = threadIdx.x;
    const int wid = tid >> 6;
    const int lane = tid & 63;

    __shared__ float xsh[DIM];
    __shared__ float red[8];
    __shared__ float logits[N_RT];

    // ---- RMSNorm (vectorized float4: 256 threads x 4 = 1024) ----
    const float4 xv = ((const float4*)(x + (size_t)t * DIM))[tid];
    float ss = xv.x*xv.x + xv.y*xv.y + xv.z*xv.z + xv.w*xv.w;
    #pragma unroll
    for (int o = 32; o > 0; o >>= 1) ss += __shfl_down(ss, o);
    if (lane == 0) red[wid] = ss;
    __syncthreads();
    if (tid == 0) {
        float s = red[0] + red[1] + red[2] + red[3];
        red[4] = rsqrtf(s * (1.0f / (float)DIM) + 1e-6f);
    }
    __syncthreads();
    const float rstd = red[4];

    const float4 wv = ((const float4*)rms_w)[tid];
    float4 nv;
    nv.x = xv.x * rstd * wv.x;
    nv.y = xv.y * rstd * wv.y;
    nv.z = xv.z * rstd * wv.z;
    nv.w = xv.w * rstd * wv.w;

    ((float4*)(xn + (size_t)t * DIM))[tid] = nv;   // scratch for expert GEMMs
    ((float4*)(y  + (size_t)t * DIM))[tid] = nv;   // residual init (full overwrite)
    ((float4*)xsh)[tid] = nv;
    __syncthreads();

    // ---- router logits: wave `wid` handles experts wid*8 .. wid*8+7 ----
    #pragma unroll
    for (int ei = 0; ei < 8; ++ei) {
        const int e = wid * 8 + ei;
        const float4* c4 = (const float4*)(cent + (size_t)e * DIM);
        float acc = 0.f;
        #pragma unroll
        for (int q = 0; q < 4; ++q) {
            float4 cv = c4[lane + 64*q];
            float4 xq = ((const float4*)xsh)[lane + 64*q];
            acc += cv.x*xq.x + cv.y*xq.y + cv.z*xq.z + cv.w*xq.w;
        }
        #pragma unroll
        for (int o = 32; o > 0; o >>= 1) acc += __shfl_down(acc, o);
        if (lane == 0) logits[e] = acc;
    }
    __syncthreads();

    // ---- softmax + top-4 on wave 0 ----
    if (wid == 0) {
        float v = (lane < N_RT) ? logits[lane] : -INFINITY;
        float m = v;
        #pragma unroll
        for (int o = 32; o > 0; o >>= 1) m = fmaxf(m, __shfl_xor(m, o));
        float p = (lane < N_RT) ? expf(v - m) : 0.f;
        float s = p;
        #pragma unroll
        for (int o = 32; o > 0; o >>= 1) s += __shfl_xor(s, o);
        const float a = p / s;
        if (lane < N_RT) aff_out[(size_t)t * N_RT + lane] = a;

        float vv = (lane < N_RT) ? a : -1.f;   // softmax probs are > 0
        for (int it = 0; it < TOPK; ++it) {
            float mx = vv;
            #pragma unroll
            for (int o = 32; o > 0; o >>= 1) mx = fmaxf(mx, __shfl_xor(mx, o));
            unsigned long long msk = __ballot(vv == mx);
            int sel = __ffsll((long long)msk) - 1;
            if (lane == 0) {
                int pos = atomicAdd(&counts[sel], 1);
                lists[(size_t)sel * T_TOK + pos]   = t;
                lscores[(size_t)sel * T_TOK + pos] = mx;
            }
            if (lane == sel) vv = -1.f;
        }
    }
}

// ---------------- Kernel B: expert MLP (shared or routed), 64-token tiles ----------------
// h = xn_tile @ W1 + b1 ; o = h @ W2 + b2 ; y += gelu(o) * score   (atomicAdd)
template<bool SHARED>
__global__ __launch_bounds__(256) void expert_kernel(
    const float* __restrict__ xn,
    const float* __restrict__ W1, const float* __restrict__ b1,
    const float* __restrict__ W2, const float* __restrict__ b2,
    const int* __restrict__ counts, const int* __restrict__ lists,
    const float* __restrict__ lscores,
    float* __restrict__ y)
{
    const int e    = blockIdx.y;
    const int tile = blockIdx.x;
    const int tid  = threadIdx.x;

    int cnt;
    if (SHARED) {
        cnt = T_TOK;
    } else {
        cnt = counts[e];
        if (tile * TB >= cnt) return;
    }

    // phase1 aliases the first 64 rows as the xn K-chunk (transposed); phase2 = hT[256][TB]
    __shared__ float smem[HDIM * LDP];           // ~69.6 KB
    __shared__ int   toks[TB];
    __shared__ float tsc[TB];
    #define XS(k, m) smem[(k) * LDP + (m)]
    #define HT(k, m) smem[(k) * LDP + (m)]

    if (tid < TB) {
        int idx = tile * TB + tid;
        if (SHARED) {
            toks[tid] = idx;
            tsc[tid]  = 1.f;
        } else if (idx < cnt) {
            toks[tid] = lists[(size_t)e * T_TOK + idx];
            tsc[tid]  = lscores[(size_t)e * T_TOK + idx];
        } else {
            toks[tid] = lists[(size_t)e * T_TOK];   // valid token, zero weight
            tsc[tid]  = 0.f;
        }
    }
    __syncthreads();

    const int m0 = (tid >> 5) * 8;   // token sub-tile   (0..56)
    const int j0 = (tid & 31) * 8;   // h-column sub-tile (0..248)

    const float* W1e = W1 + (size_t)e * DIM * HDIM;
    const float* W2e = W2 + (size_t)e * HDIM * DIM;

    float acc[8][8];
    #pragma unroll
    for (int mi = 0; mi < 8; ++mi)
        #pragma unroll
        for (int ji = 0; ji < 8; ++ji) acc[mi][ji] = 0.f;

    // ---- phase 1: h[64][256] = xn_tile @ W1 ----
    for (int kc = 0; kc < DIM; kc += 64) {
        __syncthreads();
        // stage xn chunk transposed: XS[kk][m]
        const int kq = tid & 15;
        #pragma unroll
        for (int r = 0; r < 4; ++r) {
            const int mm = (tid >> 4) + 16 * r;
            float4 v = ((const float4*)(xn + (size_t)toks[mm] * DIM + kc))[kq];
            XS(kq*4+0, mm) = v.x; XS(kq*4+1, mm) = v.y;
            XS(kq*4+2, mm) = v.z; XS(kq*4+3, mm) = v.w;
        }
        __syncthreads();

        #pragma unroll 4
        for (int kk = 0; kk < 64; ++kk) {
            const float4 a0 = *(const float4*)&XS(kk, m0);
            const float4 a1 = *(const float4*)&XS(kk, m0 + 4);
            const float* wr = W1e + (size_t)(kc + kk) * HDIM + j0;
            const float4 b0  = *(const float4*)(wr);
            const float4 b1v = *(const float4*)(wr + 4);
            const float a[8] = {a0.x,a0.y,a0.z,a0.w,a1.x,a1.y,a1.z,a1.w};
            const float b[8] = {b0.x,b0.y,b0.z,b0.w,b1v.x,b1v.y,b1v.z,b1v.w};
            #pragma unroll
            for (int mi = 0; mi < 8; ++mi)
                #pragma unroll
                for (int ji = 0; ji < 8; ++ji)
                    acc[mi][ji] = fmaf(a[mi], b[ji], acc[mi][ji]);
        }
    }

    __syncthreads();
    // write h (+b1) transposed into LDS: HT[j][m]
    #pragma unroll
    for (int ji = 0; ji < 8; ++ji) {
        const float bv = b1[(size_t)e * HDIM + j0 + ji];
        #pragma unroll
        for (int mi = 0; mi < 8; ++mi)
            HT(j0 + ji, m0 + mi) = acc[mi][ji] + bv;
    }
    __syncthreads();

    // ---- phase 2: o[64][1024] in 4 column chunks of 256 ----
    for (int jc = 0; jc < DIM; jc += 256) {
        #pragma unroll
        for (int mi = 0; mi < 8; ++mi)
            #pragma unroll
            for (int ji = 0; ji < 8; ++ji) acc[mi][ji] = 0.f;

        #pragma unroll 4
        for (int k = 0; k < HDIM; ++k) {
            const float4 a0 = *(const float4*)&HT(k, m0);
            const float4 a1 = *(const float4*)&HT(k, m0 + 4);
            const float* wr = W2e + (size_t)k * DIM + jc + j0;
            const float4 b0  = *(const float4*)(wr);
            const float4 b1v = *(const float4*)(wr + 4);
            const float a[8] = {a0.x,a0.y,a0.z,a0.w,a1.x,a1.y,a1.z,a1.w};
            const float b[8] = {b0.x,b0.y,b0.z,b0.w,b1v.x,b1v.y,b1v.z,b1v.w};
            #pragma unroll
            for (int mi = 0; mi < 8; ++mi)
                #pragma unroll
                for (int ji = 0; ji < 8; ++ji)
                    acc[mi][ji] = fmaf(a[mi], b[ji], acc[mi][ji]);
        }

        #pragma unroll
        for (int mi = 0; mi < 8; ++mi) {
            const int tok = toks[m0 + mi];
            const float sc = tsc[m0 + mi];
            float* yrow = y + (size_t)tok * DIM + jc + j0;
            #pragma unroll
            for (int ji = 0; ji < 8; ++ji) {
                const float o = acc[mi][ji] + b2[(size_t)e * DIM + jc + j0 + ji];
                atomicAdd(&yrow[ji], gelu_exact(o) * sc);
            }
        }
    }
    #undef XS
    #undef HT
}

extern "C" void kernel_launch(void* const* d_in, const int* in_sizes, int n_in,
                              void* d_out, int out_size, void* d_ws, size_t ws_size,
                              hipStream_t stream) {
    const float* x      = (const float*)d_in[0];
    const float* rms_w  = (const float*)d_in[1];
    const float* cent   = (const float*)d_in[2];
    const float* sW1    = (const float*)d_in[3];
    const float* sb1    = (const float*)d_in[4];
    const float* sW2    = (const float*)d_in[5];
    const float* sb2    = (const float*)d_in[6];
    const float* rW1    = (const float*)d_in[7];
    const float* rb1    = (const float*)d_in[8];
    const float* rW2    = (const float*)d_in[9];
    const float* rb2    = (const float*)d_in[10];

    float* y_out   = (float*)d_out;                       // [T, DIM]
    float* aff_out = (float*)d_out + (size_t)T_TOK * DIM; // [T, N_RT]

    // ws layout
    char* wsb = (char*)d_ws;
    float* xn     = (float*)wsb;                                   // 16 MB
    int*   counts = (int*)(wsb + (size_t)T_TOK * DIM * 4);         // 128 B
    int*   lists  = counts + N_RT;                                 // 512 KB
    float* lscore = (float*)(lists + (size_t)N_RT * T_TOK);        // 512 KB

    hipMemsetAsync(counts, 0, N_RT * sizeof(int), stream);

    rms_router_kernel<<<dim3(T_TOK), dim3(256), 0, stream>>>(
        x, rms_w, cent, xn, y_out, aff_out, counts, lists, lscore);

    expert_kernel<true><<<dim3(T_TOK / TB, N_SH), dim3(256), 0, stream>>>(
        xn, sW1, sb1, sW2, sb2, nullptr, nullptr, nullptr, y_out);

    expert_kernel<false><<<dim3(T_TOK / TB, N_RT), dim3(256), 0, stream>>>(
        xn, rW1, rb1, rW2, rb2, counts, lists, lscore, y_out);
}

// Round 2
// 511.676 us; speedup vs baseline: 3.3032x; 3.3032x over previous
//
#include <hip/hip_runtime.h>
#include <hip/hip_bf16.h>
#include <math.h>

#define T_TOK 4096
#define DIM   1024
#define HDIM  256
#define N_SH  2
#define N_RT  32
#define TOPK  4
#define TB    64

typedef short bf16x8 __attribute__((ext_vector_type(8)));
typedef float f32x4  __attribute__((ext_vector_type(4)));

__device__ __forceinline__ ushort f2b(float v) {
    __hip_bfloat16 h = __float2bfloat16(v);
    return *reinterpret_cast<const ushort*>(&h);
}
__device__ __forceinline__ float b2f(ushort u) {
    unsigned int x = ((unsigned int)u) << 16;
    return __uint_as_float(x);
}
__device__ __forceinline__ float gelu_tanh(float x) {
    // tanh-form GELU; max |diff| from exact erf-GELU ~3e-3
    float z = 0.7978845608028654f * (x + 0.044715f * x * x * x);
    float e = __expf(2.0f * z);
    float t = 1.0f - 2.0f / (e + 1.0f);
    return 0.5f * x * (1.0f + t);
}

// ---------------- transpose + fp32->bf16: src[E][K][N] -> dst[E][N][K] ----------------
__global__ __launch_bounds__(256) void transpose_bf16(
    const float* __restrict__ src, ushort* __restrict__ dst, int K, int N)
{
    __shared__ float t[32][33];
    const int e  = blockIdx.z;
    const float* s = src + (size_t)e * K * N;
    ushort* d      = dst + (size_t)e * K * N;
    const int n0 = blockIdx.x * 32, k0 = blockIdx.y * 32;
    const int tx = threadIdx.x, ty = threadIdx.y;   // (32, 8)
    #pragma unroll
    for (int r = 0; r < 4; ++r)
        t[ty + 8*r][tx] = s[(size_t)(k0 + ty + 8*r) * N + n0 + tx];
    __syncthreads();
    #pragma unroll
    for (int r = 0; r < 4; ++r)
        d[(size_t)(n0 + ty + 8*r) * K + k0 + tx] = f2b(t[tx][ty + 8*r]);
}

// ---------------- Kernel A: RMSNorm + router softmax + top-4 scatter ----------------
__global__ __launch_bounds__(256) void rms_router_kernel(
    const float* __restrict__ x, const float* __restrict__ rms_w,
    const float* __restrict__ cent,
    ushort* __restrict__ xnb, float* __restrict__ y, float* __restrict__ aff_out,
    int* __restrict__ counts, int* __restrict__ lists, float* __restrict__ lscores)
{
    const int t   = blockIdx.x;
    const int tid = threadIdx.x;
    const int wid = tid >> 6;
    const int lane = tid & 63;

    __shared__ float xsh[DIM];
    __shared__ float red[8];
    __shared__ float logits[N_RT];

    const float4 xv = ((const float4*)(x + (size_t)t * DIM))[tid];
    float ss = xv.x*xv.x + xv.y*xv.y + xv.z*xv.z + xv.w*xv.w;
    #pragma unroll
    for (int o = 32; o > 0; o >>= 1) ss += __shfl_down(ss, o);
    if (lane == 0) red[wid] = ss;
    __syncthreads();
    if (tid == 0) {
        float s = red[0] + red[1] + red[2] + red[3];
        red[4] = rsqrtf(s * (1.0f / (float)DIM) + 1e-6f);
    }
    __syncthreads();
    const float rstd = red[4];

    const float4 wv = ((const float4*)rms_w)[tid];
    float4 nv;
    nv.x = xv.x * rstd * wv.x;
    nv.y = xv.y * rstd * wv.y;
    nv.z = xv.z * rstd * wv.z;
    nv.w = xv.w * rstd * wv.w;

    ((float4*)(y + (size_t)t * DIM))[tid] = nv;     // residual init
    ushort4 xb = make_ushort4(f2b(nv.x), f2b(nv.y), f2b(nv.z), f2b(nv.w));
    ((ushort4*)(xnb + (size_t)t * DIM))[tid] = xb;  // bf16 operand for experts
    ((float4*)xsh)[tid] = nv;
    __syncthreads();

    #pragma unroll
    for (int ei = 0; ei < 8; ++ei) {
        const int e = wid * 8 + ei;
        const float4* c4 = (const float4*)(cent + (size_t)e * DIM);
        float acc = 0.f;
        #pragma unroll
        for (int q = 0; q < 4; ++q) {
            float4 cv = c4[lane + 64*q];
            float4 xq = ((const float4*)xsh)[lane + 64*q];
            acc += cv.x*xq.x + cv.y*xq.y + cv.z*xq.z + cv.w*xq.w;
        }
        #pragma unroll
        for (int o = 32; o > 0; o >>= 1) acc += __shfl_down(acc, o);
        if (lane == 0) logits[e] = acc;
    }
    __syncthreads();

    if (wid == 0) {
        float v = (lane < N_RT) ? logits[lane] : -INFINITY;
        float m = v;
        #pragma unroll
        for (int o = 32; o > 0; o >>= 1) m = fmaxf(m, __shfl_xor(m, o));
        float p = (lane < N_RT) ? expf(v - m) : 0.f;
        float s = p;
        #pragma unroll
        for (int o = 32; o > 0; o >>= 1) s += __shfl_xor(s, o);
        const float a = p / s;
        if (lane < N_RT) aff_out[(size_t)t * N_RT + lane] = a;

        float vv = (lane < N_RT) ? a : -1.f;
        for (int it = 0; it < TOPK; ++it) {
            float mx = vv;
            #pragma unroll
            for (int o = 32; o > 0; o >>= 1) mx = fmaxf(mx, __shfl_xor(mx, o));
            unsigned long long msk = __ballot(vv == mx);
            int sel = __ffsll((long long)msk) - 1;
            if (lane == 0) {
                int pos = atomicAdd(&counts[sel], 1);
                lists[(size_t)sel * T_TOK + pos]   = (t << 2) | it;   // token + slot
                lscores[(size_t)sel * T_TOK + pos] = mx;
            }
            if (lane == sel) vv = -1.f;
        }
    }
}

// ---------------- Kernel B: fused 2-layer expert MLP with bf16 MFMA ----------------
// blockIdx.y: 0..1 shared experts (all tokens), 2..33 routed experts.
// C1[64,256] = X @ W1 (K=1024); h=bf16(C1+b1) in swizzled LDS;
// C2[64,1024] = h @ W2 (K=256); out = gelu(C2+b2)*score -> slot buffer (or atomic y).
template<bool ATOMIC>
__global__ __launch_bounds__(256, 3) void moe_expert_mfma(
    const ushort* __restrict__ xnb,
    const ushort* __restrict__ W1ts, const float* __restrict__ sb1,
    const ushort* __restrict__ W2ts, const float* __restrict__ sb2,
    const ushort* __restrict__ W1tr, const float* __restrict__ rb1,
    const ushort* __restrict__ W2tr, const float* __restrict__ rb2,
    const int* __restrict__ counts, const int* __restrict__ lists,
    const float* __restrict__ lscores,
    ushort* __restrict__ sbuf, float* __restrict__ y)
{
    const int ey   = blockIdx.y;
    const int tile = blockIdx.x;
    const int tid  = threadIdx.x;

    const ushort *W1t, *W2t; const float *b1, *b2;
    if (ey < N_SH) {
        W1t = W1ts + (size_t)ey * HDIM * DIM;
        W2t = W2ts + (size_t)ey * DIM * HDIM;
        b1  = sb1 + ey * HDIM;  b2 = sb2 + ey * DIM;
    } else {
        const int e = ey - N_SH;
        if (tile * TB >= counts[e]) return;
        W1t = W1tr + (size_t)e * HDIM * DIM;
        W2t = W2tr + (size_t)e * DIM * HDIM;
        b1  = rb1 + e * HDIM;  b2 = rb2 + e * DIM;
    }

    __shared__ ushort hlds[TB * HDIM];   // 32 KB, XOR-swizzled
    __shared__ int   toksA[TB];
    __shared__ int   orow[TB];
    __shared__ float tscs[TB];

    if (tid < TB) {
        if (ey < N_SH) {
            const int t = tile * TB + tid;
            toksA[tid] = t;
            orow[tid]  = ATOMIC ? t : t * 6 + ey;
            tscs[tid]  = 1.f;
        } else {
            const int e   = ey - N_SH;
            const int cnt = counts[e];
            const int idx = tile * TB + tid;
            if (idx < cnt) {
                const int v = lists[(size_t)e * T_TOK + idx];
                const int t = v >> 2;
                toksA[tid] = t;
                orow[tid]  = ATOMIC ? t : t * 6 + 2 + (v & 3);
                tscs[tid]  = lscores[(size_t)e * T_TOK + idx];
            } else {
                const int t0 = lists[(size_t)e * T_TOK] >> 2;  // any valid row
                toksA[tid] = t0;
                orow[tid]  = ATOMIC ? t0 : (T_TOK + tid) * 6;  // dummy region
                tscs[tid]  = 0.f;
            }
        }
    }
    __syncthreads();

    const int w    = tid >> 6;      // wave -> n-range w*64
    const int lane = tid & 63;
    const int l16  = lane & 15;
    const int lk   = lane >> 4;

    // A fragment row pointers (rows = tokens, 4 M-frags cover all 64)
    const ushort* aptr[4];
    #pragma unroll
    for (int mi = 0; mi < 4; ++mi)
        aptr[mi] = xnb + (size_t)toksA[mi * 16 + l16] * DIM + lk * 8;

    f32x4 acc[4][4];
    #pragma unroll
    for (int mi = 0; mi < 4; ++mi)
        #pragma unroll
        for (int ni = 0; ni < 4; ++ni) acc[mi][ni] = (f32x4){0.f, 0.f, 0.f, 0.f};

    const ushort* bbase1 = W1t + (size_t)(w * 64 + l16) * DIM + lk * 8;

    // ---- phase 1: K = 1024 ----
    for (int k0 = 0; k0 < DIM; k0 += 32) {
        bf16x8 a[4];
        #pragma unroll
        for (int mi = 0; mi < 4; ++mi)
            a[mi] = *(const bf16x8*)(aptr[mi] + k0);
        #pragma unroll
        for (int ni = 0; ni < 4; ++ni) {
            bf16x8 b = *(const bf16x8*)(bbase1 + (size_t)ni * 16 * DIM + k0);
            #pragma unroll
            for (int mi = 0; mi < 4; ++mi)
                acc[mi][ni] = __builtin_amdgcn_mfma_f32_16x16x32_bf16(a[mi], b, acc[mi][ni], 0, 0, 0);
        }
    }

    // h = acc + b1 -> bf16 -> swizzled LDS  (byte ^ ((row&7)<<4) kills 16-way conflicts)
    #pragma unroll
    for (int ni = 0; ni < 4; ++ni) {
        const int n   = w * 64 + ni * 16 + l16;
        const float bv = b1[n];
        #pragma unroll
        for (int mi = 0; mi < 4; ++mi) {
            #pragma unroll
            for (int r = 0; r < 4; ++r) {
                const int m = mi * 16 + lk * 4 + r;
                const int byte = (m * (HDIM * 2) + n * 2) ^ ((m & 7) << 4);
                *(ushort*)((char*)hlds + byte) = f2b(acc[mi][ni][r] + bv);
            }
        }
    }
    __syncthreads();

    // ---- phase 2: K = 256, N = 1024 in 4 chunks of 256 ----
    for (int jc = 0; jc < DIM; jc += 256) {
        f32x4 acc2[4][4];
        #pragma unroll
        for (int mi = 0; mi < 4; ++mi)
            #pragma unroll
            for (int ni = 0; ni < 4; ++ni) acc2[mi][ni] = (f32x4){0.f, 0.f, 0.f, 0.f};

        for (int k0 = 0; k0 < HDIM; k0 += 32) {
            bf16x8 a[4];
            #pragma unroll
            for (int mi = 0; mi < 4; ++mi) {
                const int m = mi * 16 + l16;
                const int byte = (m * (HDIM * 2) + (k0 + lk * 8) * 2) ^ ((m & 7) << 4);
                a[mi] = *(const bf16x8*)((const char*)hlds + byte);
            }
            #pragma unroll
            for (int ni = 0; ni < 4; ++ni) {
                const ushort* bp = W2t + (size_t)(jc + w * 64 + ni * 16 + l16) * HDIM + k0 + lk * 8;
                bf16x8 b = *(const bf16x8*)bp;
                #pragma unroll
                for (int mi = 0; mi < 4; ++mi)
                    acc2[mi][ni] = __builtin_amdgcn_mfma_f32_16x16x32_bf16(a[mi], b, acc2[mi][ni], 0, 0, 0);
            }
        }

        #pragma unroll
        for (int ni = 0; ni < 4; ++ni) {
            const int n   = jc + w * 64 + ni * 16 + l16;
            const float bv = b2[n];
            #pragma unroll
            for (int mi = 0; mi < 4; ++mi) {
                #pragma unroll
                for (int r = 0; r < 4; ++r) {
                    const int mloc = mi * 16 + lk * 4 + r;
                    const float o   = acc2[mi][ni][r] + bv;
                    const float val = gelu_tanh(o) * tscs[mloc];
                    if (ATOMIC) atomicAdd(&y[(size_t)orow[mloc] * DIM + n], val);
                    else        sbuf[(size_t)orow[mloc] * DIM + n] = f2b(val);
                }
            }
        }
    }
}

// ---------------- gather: y += sum of 6 slots ----------------
__global__ __launch_bounds__(256) void gather_kernel(
    const ushort* __restrict__ sbuf, float* __restrict__ y)
{
    const int idx = blockIdx.x * 256 + threadIdx.x;   // over T*DIM/4
    const int t  = idx >> 8;
    const int d  = (idx & 255) * 4;
    float4 a = ((float4*)y)[idx];
    #pragma unroll
    for (int s = 0; s < 6; ++s) {
        const ushort4 u = *(const ushort4*)(sbuf + ((size_t)t * 6 + s) * DIM + d);
        a.x += b2f(u.x); a.y += b2f(u.y); a.z += b2f(u.z); a.w += b2f(u.w);
    }
    ((float4*)y)[idx] = a;
}

extern "C" void kernel_launch(void* const* d_in, const int* in_sizes, int n_in,
                              void* d_out, int out_size, void* d_ws, size_t ws_size,
                              hipStream_t stream) {
    const float* x      = (const float*)d_in[0];
    const float* rms_w  = (const float*)d_in[1];
    const float* cent   = (const float*)d_in[2];
    const float* sW1    = (const float*)d_in[3];
    const float* sb1    = (const float*)d_in[4];
    const float* sW2    = (const float*)d_in[5];
    const float* sb2    = (const float*)d_in[6];
    const float* rW1    = (const float*)d_in[7];
    const float* rb1    = (const float*)d_in[8];
    const float* rW2    = (const float*)d_in[9];
    const float* rb2    = (const float*)d_in[10];

    float* y_out   = (float*)d_out;
    float* aff_out = (float*)d_out + (size_t)T_TOK * DIM;

    char* p = (char*)d_ws;
    size_t off = 0;
    auto take = [&](size_t b) {
        char* r = p + off;
        off += (b + 255) & ~(size_t)255;
        return r;
    };
    ushort* xnb   = (ushort*)take((size_t)T_TOK * DIM * 2);
    ushort* W1ts  = (ushort*)take((size_t)N_SH * HDIM * DIM * 2);
    ushort* W2ts  = (ushort*)take((size_t)N_SH * DIM * HDIM * 2);
    ushort* W1tr  = (ushort*)take((size_t)N_RT * HDIM * DIM * 2);
    ushort* W2tr  = (ushort*)take((size_t)N_RT * DIM * HDIM * 2);
    int*    counts= (int*)take(N_RT * sizeof(int));
    int*    lists = (int*)take((size_t)N_RT * T_TOK * 4);
    float*  lsc   = (float*)take((size_t)N_RT * T_TOK * 4);
    ushort* sbuf  = (ushort*)take((size_t)(T_TOK + TB) * 6 * DIM * 2);
    const bool slot_ok = (off <= ws_size);

    hipMemsetAsync(counts, 0, N_RT * sizeof(int), stream);

    // weight transpose + bf16 convert (W[E][K][N] -> Wt[E][N][K])
    transpose_bf16<<<dim3(HDIM/32, DIM/32, N_SH), dim3(32, 8), 0, stream>>>(sW1, W1ts, DIM, HDIM);
    transpose_bf16<<<dim3(DIM/32, HDIM/32, N_SH), dim3(32, 8), 0, stream>>>(sW2, W2ts, HDIM, DIM);
    transpose_bf16<<<dim3(HDIM/32, DIM/32, N_RT), dim3(32, 8), 0, stream>>>(rW1, W1tr, DIM, HDIM);
    transpose_bf16<<<dim3(DIM/32, HDIM/32, N_RT), dim3(32, 8), 0, stream>>>(rW2, W2tr, HDIM, DIM);

    rms_router_kernel<<<dim3(T_TOK), dim3(256), 0, stream>>>(
        x, rms_w, cent, xnb, y_out, aff_out, counts, lists, lsc);

    if (slot_ok) {
        moe_expert_mfma<false><<<dim3(T_TOK / TB, N_SH + N_RT), dim3(256), 0, stream>>>(
            xnb, W1ts, sb1, W2ts, sb2, W1tr, rb1, W2tr, rb2, counts, lists, lsc, sbuf, y_out);
        gather_kernel<<<dim3((T_TOK * DIM / 4) / 256), dim3(256), 0, stream>>>(sbuf, y_out);
    } else {
        moe_expert_mfma<true><<<dim3(T_TOK / TB, N_SH + N_RT), dim3(256), 0, stream>>>(
            xnb, W1ts, sb1, W2ts, sb2, W1tr, rb1, W2tr, rb2, counts, lists, lsc, sbuf, y_out);
    }
}

// Round 3
// 248.044 us; speedup vs baseline: 6.8139x; 2.0628x over previous
//
#include <hip/hip_runtime.h>
#include <hip/hip_bf16.h>
#include <math.h>

#define T_TOK 4096
#define DIM   1024
#define HDIM  256
#define N_SH  2
#define N_RT  32
#define N_E   34
#define TOPK  4
#define TB    32
#define MAXPB 520
#define NSLOT 6

typedef short bf16x8 __attribute__((ext_vector_type(8)));
typedef float f32x4  __attribute__((ext_vector_type(4)));
typedef unsigned short u16x8 __attribute__((ext_vector_type(8)));

__device__ __forceinline__ ushort f2b(float v) {
    __hip_bfloat16 h = __float2bfloat16(v);
    return *reinterpret_cast<const ushort*>(&h);
}
__device__ __forceinline__ float b2f(ushort u) {
    unsigned int x = ((unsigned int)u) << 16;
    return __uint_as_float(x);
}
__device__ __forceinline__ float gelu_tanh(float x) {
    float z = 0.7978845608028654f * (x + 0.044715f * x * x * x);
    float e = __expf(2.0f * z);
    float t = 1.0f - 2.0f / (e + 1.0f);
    return 0.5f * x * (1.0f + t);
}

// ---- pack weights: src[E][K][N] fp32 -> per-MFMA-fragment bf16 tiles ----
// tile (n16,k32) holds 16n x 32k; lane l = lk*16+l16 stores 8 bf16 of
// (n = n16*16+l16, k = k32*32+lk*8 .. +8) at tile*512 + l*8  (1KB/tile)
template<int K, int N>
__global__ __launch_bounds__(256) void pack_weights(
    const float* __restrict__ srcS, const float* __restrict__ srcR,
    ushort* __restrict__ dst)
{
    const int e = blockIdx.y;
    const float* src = (e < N_SH) ? (srcS + (size_t)e * K * N)
                                  : (srcR + (size_t)(e - N_SH) * K * N);
    const int tid  = threadIdx.x;
    const int tile = blockIdx.x * 4 + (tid >> 6);
    const int lane = tid & 63;
    const int l16 = lane & 15, lk = lane >> 4;
    const int n16 = tile / (K / 32), k32 = tile % (K / 32);
    const int n  = n16 * 16 + l16;
    const int kb = k32 * 32 + lk * 8;
    const float* s = src + (size_t)kb * N + n;
    u16x8 o;
    #pragma unroll
    for (int j = 0; j < 8; ++j) o[j] = f2b(s[(size_t)j * N]);
    *(u16x8*)(dst + (size_t)e * K * N + (size_t)tile * 512 + lane * 8) = o;
}

// ---------------- RMSNorm + router softmax + top-4 scatter ----------------
__global__ __launch_bounds__(256) void rms_router_kernel(
    const float* __restrict__ x, const float* __restrict__ rms_w,
    const float* __restrict__ cent,
    ushort* __restrict__ xnb, float* __restrict__ y, float* __restrict__ aff_out,
    int* __restrict__ counts, int* __restrict__ lists, float* __restrict__ sscore)
{
    const int t   = blockIdx.x;
    const int tid = threadIdx.x;
    const int wid = tid >> 6;
    const int lane = tid & 63;

    __shared__ float xsh[DIM];
    __shared__ float red[8];
    __shared__ float logits[N_RT];

    const float4 xv = ((const float4*)(x + (size_t)t * DIM))[tid];
    float ss = xv.x*xv.x + xv.y*xv.y + xv.z*xv.z + xv.w*xv.w;
    #pragma unroll
    for (int o = 32; o > 0; o >>= 1) ss += __shfl_down(ss, o);
    if (lane == 0) red[wid] = ss;
    __syncthreads();
    if (tid == 0) {
        float s = red[0] + red[1] + red[2] + red[3];
        red[4] = rsqrtf(s * (1.0f / (float)DIM) + 1e-6f);
    }
    __syncthreads();
    const float rstd = red[4];

    const float4 wv = ((const float4*)rms_w)[tid];
    float4 nv;
    nv.x = xv.x * rstd * wv.x;
    nv.y = xv.y * rstd * wv.y;
    nv.z = xv.z * rstd * wv.z;
    nv.w = xv.w * rstd * wv.w;

    ((float4*)(y + (size_t)t * DIM))[tid] = nv;     // residual init (fp32 xn)
    ushort4 xb = make_ushort4(f2b(nv.x), f2b(nv.y), f2b(nv.z), f2b(nv.w));
    ((ushort4*)(xnb + (size_t)t * DIM))[tid] = xb;
    ((float4*)xsh)[tid] = nv;
    __syncthreads();

    #pragma unroll
    for (int ei = 0; ei < 8; ++ei) {
        const int e = wid * 8 + ei;
        const float4* c4 = (const float4*)(cent + (size_t)e * DIM);
        float acc = 0.f;
        #pragma unroll
        for (int q = 0; q < 4; ++q) {
            float4 cv = c4[lane + 64*q];
            float4 xq = ((const float4*)xsh)[lane + 64*q];
            acc += cv.x*xq.x + cv.y*xq.y + cv.z*xq.z + cv.w*xq.w;
        }
        #pragma unroll
        for (int o = 32; o > 0; o >>= 1) acc += __shfl_down(acc, o);
        if (lane == 0) logits[e] = acc;
    }
    __syncthreads();

    if (wid == 0) {
        float v = (lane < N_RT) ? logits[lane] : -INFINITY;
        float m = v;
        #pragma unroll
        for (int o = 32; o > 0; o >>= 1) m = fmaxf(m, __shfl_xor(m, o));
        float p = (lane < N_RT) ? expf(v - m) : 0.f;
        float s = p;
        #pragma unroll
        for (int o = 32; o > 0; o >>= 1) s += __shfl_xor(s, o);
        const float a = p / s;
        if (lane < N_RT) aff_out[(size_t)t * N_RT + lane] = a;
        if (lane < N_SH) sscore[(size_t)t * NSLOT + lane] = 1.f;

        float vv = (lane < N_RT) ? a : -1.f;
        for (int it = 0; it < TOPK; ++it) {
            float mx = vv;
            #pragma unroll
            for (int o = 32; o > 0; o >>= 1) mx = fmaxf(mx, __shfl_xor(mx, o));
            unsigned long long msk = __ballot(vv == mx);
            int sel = __ffsll((long long)msk) - 1;
            if (lane == 0) {
                int pos = atomicAdd(&counts[sel], 1);
                lists[(size_t)sel * T_TOK + pos] = (t << 2) | it;
                sscore[(size_t)t * NSLOT + 2 + it] = mx;
            }
            if (lane == sel) vv = -1.f;
        }
    }
}

// ---- build XCD-bucketed work items: bucket b = e%8 gets expert e's tiles ----
__global__ void build_items(const int* __restrict__ counts,
                            int* __restrict__ bucket_cnt, int* __restrict__ items)
{
    const int e = threadIdx.x;           // 64 launched, 32 active
    int tiles = 0;
    if (e < N_RT) tiles = (counts[e] + TB - 1) / TB;
    const int grp = e >> 3;
    int pre = 0;
    #pragma unroll
    for (int g = 0; g < 4; ++g) {
        int tg = __shfl(tiles, (e & 7) + 8 * g, 64);
        if (g < grp) pre += tg;
    }
    if (e < N_RT) {
        for (int i = 0; i < tiles; ++i)
            items[(e & 7) * MAXPB + pre + i] = (e << 16) | i;
        if (grp == 3) bucket_cnt[e & 7] = pre + tiles;
    }
}

// ---------------- fused 2-layer expert MLP, bf16 MFMA, 32-token tiles ----------------
template<bool ATOMIC>
__global__ __launch_bounds__(256, 3) void moe_mfma(
    const ushort* __restrict__ xnb,
    const ushort* __restrict__ W1p, const ushort* __restrict__ W2p,
    const float* __restrict__ sb1, const float* __restrict__ sb2,
    const float* __restrict__ rb1, const float* __restrict__ rb2,
    const int* __restrict__ counts, const int* __restrict__ lists,
    const int* __restrict__ bucket_cnt, const int* __restrict__ items,
    const float* __restrict__ sscore,
    ushort* __restrict__ sbuf, float* __restrict__ y)
{
    const int bi  = blockIdx.x;
    const int tid = threadIdx.x;

    __shared__ int    toks[TB];
    __shared__ int    orow[TB];
    __shared__ float  tscs[TB];
    __shared__ ushort hlds[TB * HDIM];       // 16 KB, XOR-swizzled
    __shared__ ushort ostage[4 * 32 * 72];   // 18 KB, per-wave repack

    int e_full;
    const float *b1, *b2;

    if (bi < 256) {                           // shared experts: 128 tiles x 2
        e_full = bi >> 7;
        const int tile = bi & 127;
        if (tid < TB) {
            const int t = tile * TB + tid;
            toks[tid] = t;
            orow[tid] = ATOMIC ? t : t * NSLOT + e_full;
            tscs[tid] = 1.f;
        }
        b1 = sb1 + e_full * HDIM;  b2 = sb2 + e_full * DIM;
    } else {                                  // routed: bucketed queue
        const int j = bi - 256;
        const int b = j & 7, pos = j >> 3;
        if (pos >= bucket_cnt[b]) return;
        const int v = items[b * MAXPB + pos];
        const int e = v >> 16, tile = v & 0xffff;
        e_full = N_SH + e;
        const int cnt = counts[e];
        if (tid < TB) {
            const int idx = tile * TB + tid;
            if (idx < cnt) {
                const int lv = lists[(size_t)e * T_TOK + idx];
                const int t = lv >> 2;
                toks[tid] = t;
                orow[tid] = ATOMIC ? t : t * NSLOT + 2 + (lv & 3);
                tscs[tid] = ATOMIC ? sscore[(size_t)t * NSLOT + 2 + (lv & 3)] : 0.f;
            } else {
                toks[tid] = 0;
                orow[tid] = ATOMIC ? 0 : T_TOK * NSLOT;   // dummy row
                tscs[tid] = 0.f;
            }
        }
        b1 = rb1 + e * HDIM;  b2 = rb2 + e * DIM;
    }
    __syncthreads();

    const int w = tid >> 6, lane = tid & 63;
    const int l16 = lane & 15, lk = lane >> 4;

    const ushort* abase[2];
    #pragma unroll
    for (int mi = 0; mi < 2; ++mi)
        abase[mi] = xnb + (size_t)toks[mi * 16 + l16] * DIM + lk * 8;

    const ushort* W1e = W1p + (size_t)e_full * DIM * HDIM;
    const ushort* bbase[4];
    #pragma unroll
    for (int ni = 0; ni < 4; ++ni)
        bbase[ni] = W1e + (size_t)((w * 4 + ni) * 32) * 512 + lane * 8;

    f32x4 acc[2][4];
    #pragma unroll
    for (int mi = 0; mi < 2; ++mi)
        #pragma unroll
        for (int ni = 0; ni < 4; ++ni) acc[mi][ni] = (f32x4){0.f,0.f,0.f,0.f};

    // ---- phase 1: C1[32,256] = X @ W1, K=1024, 1-deep register prefetch ----
    bf16x8 ac[2], bc[4];
    #pragma unroll
    for (int mi = 0; mi < 2; ++mi) ac[mi] = *(const bf16x8*)abase[mi];
    #pragma unroll
    for (int ni = 0; ni < 4; ++ni) bc[ni] = *(const bf16x8*)bbase[ni];

    #pragma unroll
    for (int k32 = 0; k32 < 32; ++k32) {
        bf16x8 an[2], bn[4];
        if (k32 < 31) {
            #pragma unroll
            for (int ni = 0; ni < 4; ++ni)
                bn[ni] = *(const bf16x8*)(bbase[ni] + (size_t)(k32 + 1) * 512);
            #pragma unroll
            for (int mi = 0; mi < 2; ++mi)
                an[mi] = *(const bf16x8*)(abase[mi] + (k32 + 1) * 32);
        }
        #pragma unroll
        for (int ni = 0; ni < 4; ++ni)
            #pragma unroll
            for (int mi = 0; mi < 2; ++mi)
                acc[mi][ni] = __builtin_amdgcn_mfma_f32_16x16x32_bf16(ac[mi], bc[ni], acc[mi][ni], 0, 0, 0);
        if (k32 < 31) {
            #pragma unroll
            for (int ni = 0; ni < 4; ++ni) bc[ni] = bn[ni];
            #pragma unroll
            for (int mi = 0; mi < 2; ++mi) ac[mi] = an[mi];
        }
    }

    // h = bf16(C1 + b1) -> swizzled LDS
    #pragma unroll
    for (int ni = 0; ni < 4; ++ni) {
        const int n = w * 64 + ni * 16 + l16;
        const float bv = b1[n];
        #pragma unroll
        for (int mi = 0; mi < 2; ++mi) {
            #pragma unroll
            for (int r = 0; r < 4; ++r) {
                const int m = mi * 16 + lk * 4 + r;
                const int byte = (m * (HDIM * 2) + n * 2) ^ ((m & 7) << 4);
                *(ushort*)((char*)hlds + byte) = f2b(acc[mi][ni][r] + bv);
            }
        }
    }
    __syncthreads();

    // ---- phase 2: C2[32,1024] = h @ W2, K=256, 4 column chunks ----
    const ushort* W2e = W2p + (size_t)e_full * HDIM * DIM;
    for (int jc = 0; jc < 4; ++jc) {
        f32x4 acc2[2][4];
        #pragma unroll
        for (int mi = 0; mi < 2; ++mi)
            #pragma unroll
            for (int ni = 0; ni < 4; ++ni) acc2[mi][ni] = (f32x4){0.f,0.f,0.f,0.f};

        const ushort* b2base[4];
        #pragma unroll
        for (int ni = 0; ni < 4; ++ni)
            b2base[ni] = W2e + (size_t)((jc * 16 + w * 4 + ni) * 8) * 512 + lane * 8;

        bf16x8 bc2[4];
        #pragma unroll
        for (int ni = 0; ni < 4; ++ni) bc2[ni] = *(const bf16x8*)b2base[ni];

        #pragma unroll
        for (int k32 = 0; k32 < 8; ++k32) {
            bf16x8 a2[2];
            #pragma unroll
            for (int mi = 0; mi < 2; ++mi) {
                const int m = mi * 16 + l16;
                const int byte = (m * (HDIM * 2) + (k32 * 32 + lk * 8) * 2) ^ ((m & 7) << 4);
                a2[mi] = *(const bf16x8*)((const char*)hlds + byte);
            }
            bf16x8 bn2[4];
            if (k32 < 7) {
                #pragma unroll
                for (int ni = 0; ni < 4; ++ni)
                    bn2[ni] = *(const bf16x8*)(b2base[ni] + (size_t)(k32 + 1) * 512);
            }
            #pragma unroll
            for (int ni = 0; ni < 4; ++ni)
                #pragma unroll
                for (int mi = 0; mi < 2; ++mi)
                    acc2[mi][ni] = __builtin_amdgcn_mfma_f32_16x16x32_bf16(a2[mi], bc2[ni], acc2[mi][ni], 0, 0, 0);
            if (k32 < 7) {
                #pragma unroll
                for (int ni = 0; ni < 4; ++ni) bc2[ni] = bn2[ni];
            }
        }

        if (ATOMIC) {
            #pragma unroll
            for (int ni = 0; ni < 4; ++ni) {
                const int n = jc * 256 + w * 64 + ni * 16 + l16;
                const float bv = b2[n];
                #pragma unroll
                for (int mi = 0; mi < 2; ++mi)
                    #pragma unroll
                    for (int r = 0; r < 4; ++r) {
                        const int m = mi * 16 + lk * 4 + r;
                        const float val = gelu_tanh(acc2[mi][ni][r] + bv) * tscs[m];
                        atomicAdd(&y[(size_t)orow[m] * DIM + n], val);
                    }
            }
        } else {
            // repack via per-wave LDS -> coalesced ushort8 stores (pre-gelu, pre-score)
            ushort* os = ostage + w * (32 * 72);
            asm volatile("s_waitcnt lgkmcnt(0)" ::: "memory");
            #pragma unroll
            for (int ni = 0; ni < 4; ++ni) {
                const float bv = b2[jc * 256 + w * 64 + ni * 16 + l16];
                #pragma unroll
                for (int mi = 0; mi < 2; ++mi)
                    #pragma unroll
                    for (int r = 0; r < 4; ++r) {
                        const int m = mi * 16 + lk * 4 + r;
                        os[m * 72 + ni * 16 + l16] = f2b(acc2[mi][ni][r] + bv);
                    }
            }
            asm volatile("s_waitcnt lgkmcnt(0)" ::: "memory");
            #pragma unroll
            for (int rr = 0; rr < 4; ++rr) {
                const int m  = rr * 8 + (lane >> 3);
                const int nl = (lane & 7) * 8;
                u16x8 vv = *(const u16x8*)(os + m * 72 + nl);
                *(u16x8*)(sbuf + (size_t)orow[m] * DIM + jc * 256 + w * 64 + nl) = vv;
            }
        }
    }
}

// ---------------- gather: y = xn + sum_s gelu(slot)*score ----------------
__global__ __launch_bounds__(256) void gather_kernel(
    const ushort* __restrict__ sbuf, const float* __restrict__ sscore,
    float* __restrict__ y)
{
    const int idx = blockIdx.x * 256 + threadIdx.x;   // over T*DIM/4
    const int t = idx >> 8;
    const int d = (idx & 255) * 4;
    float4 a = ((float4*)y)[idx];
    #pragma unroll
    for (int s = 0; s < NSLOT; ++s) {
        const float sc = sscore[(size_t)t * NSLOT + s];
        const ushort4 u = *(const ushort4*)(sbuf + ((size_t)t * NSLOT + s) * DIM + d);
        a.x += gelu_tanh(b2f(u.x)) * sc;
        a.y += gelu_tanh(b2f(u.y)) * sc;
        a.z += gelu_tanh(b2f(u.z)) * sc;
        a.w += gelu_tanh(b2f(u.w)) * sc;
    }
    ((float4*)y)[idx] = a;
}

extern "C" void kernel_launch(void* const* d_in, const int* in_sizes, int n_in,
                              void* d_out, int out_size, void* d_ws, size_t ws_size,
                              hipStream_t stream) {
    const float* x      = (const float*)d_in[0];
    const float* rms_w  = (const float*)d_in[1];
    const float* cent   = (const float*)d_in[2];
    const float* sW1    = (const float*)d_in[3];
    const float* sb1    = (const float*)d_in[4];
    const float* sW2    = (const float*)d_in[5];
    const float* sb2    = (const float*)d_in[6];
    const float* rW1    = (const float*)d_in[7];
    const float* rb1    = (const float*)d_in[8];
    const float* rW2    = (const float*)d_in[9];
    const float* rb2    = (const float*)d_in[10];

    float* y_out   = (float*)d_out;
    float* aff_out = (float*)d_out + (size_t)T_TOK * DIM;

    char* p = (char*)d_ws;
    size_t off = 0;
    auto take = [&](size_t b) {
        char* r = p + off;
        off += (b + 255) & ~(size_t)255;
        return r;
    };
    ushort* xnb    = (ushort*)take((size_t)T_TOK * DIM * 2);
    ushort* W1p    = (ushort*)take((size_t)N_E * DIM * HDIM * 2);
    ushort* W2p    = (ushort*)take((size_t)N_E * HDIM * DIM * 2);
    int*    counts = (int*)take(N_RT * sizeof(int));
    int*    lists  = (int*)take((size_t)N_RT * T_TOK * 4);
    float*  sscore = (float*)take((size_t)T_TOK * NSLOT * 4);
    int*    bcnt   = (int*)take(8 * sizeof(int));
    int*    items  = (int*)take((size_t)8 * MAXPB * 4);
    ushort* sbuf   = (ushort*)take(((size_t)T_TOK * NSLOT + 32) * DIM * 2);
    const bool slot_ok = (off <= ws_size);

    hipMemsetAsync(counts, 0, N_RT * sizeof(int), stream);

    pack_weights<DIM,  HDIM><<<dim3(128, N_E), dim3(256), 0, stream>>>(sW1, rW1, W1p);
    pack_weights<HDIM, DIM ><<<dim3(128, N_E), dim3(256), 0, stream>>>(sW2, rW2, W2p);

    rms_router_kernel<<<dim3(T_TOK), dim3(256), 0, stream>>>(
        x, rms_w, cent, xnb, y_out, aff_out, counts, lists, sscore);

    build_items<<<dim3(1), dim3(64), 0, stream>>>(counts, bcnt, items);

    const int grid = 256 + 8 * MAXPB;
    if (slot_ok) {
        moe_mfma<false><<<dim3(grid), dim3(256), 0, stream>>>(
            xnb, W1p, W2p, sb1, sb2, rb1, rb2, counts, lists, bcnt, items,
            sscore, sbuf, y_out);
        gather_kernel<<<dim3((T_TOK * DIM / 4) / 256), dim3(256), 0, stream>>>(
            sbuf, sscore, y_out);
    } else {
        moe_mfma<true><<<dim3(grid), dim3(256), 0, stream>>>(
            xnb, W1p, W2p, sb1, sb2, rb1, rb2, counts, lists, bcnt, items,
            sscore, sbuf, y_out);
    }
}

// Round 5
// 187.195 us; speedup vs baseline: 9.0288x; 1.3251x over previous
//
#include <hip/hip_runtime.h>
#include <hip/hip_bf16.h>
#include <math.h>

#define T_TOK 4096
#define DIM   1024
#define HDIM  256
#define N_SH  2
#define N_RT  32
#define N_E   34
#define TOPK  4
#define TB    32
#define MAXPB 520
#define NSLOT 6

typedef short bf16x8 __attribute__((ext_vector_type(8)));
typedef float f32x4  __attribute__((ext_vector_type(4)));
typedef unsigned short u16x8 __attribute__((ext_vector_type(8)));

__device__ __forceinline__ ushort f2b(float v) {
    __hip_bfloat16 h = __float2bfloat16(v);
    return *reinterpret_cast<const ushort*>(&h);
}
__device__ __forceinline__ float b2f(ushort u) {
    unsigned int x = ((unsigned int)u) << 16;
    return __uint_as_float(x);
}
__device__ __forceinline__ float gelu_tanh(float x) {
    float z = 0.7978845608028654f * (x + 0.044715f * x * x * x);
    float e = __expf(2.0f * z);
    float t = 1.0f - 2.0f / (e + 1.0f);
    return 0.5f * x * (1.0f + t);
}

// ---- pack weights: src[E][K][N] fp32 -> per-MFMA-fragment bf16 tiles ----
template<int K, int N>
__global__ __launch_bounds__(256) void pack_weights(
    const float* __restrict__ srcS, const float* __restrict__ srcR,
    ushort* __restrict__ dst)
{
    const int e = blockIdx.y;
    const float* src = (e < N_SH) ? (srcS + (size_t)e * K * N)
                                  : (srcR + (size_t)(e - N_SH) * K * N);
    const int tid  = threadIdx.x;
    const int tile = blockIdx.x * 4 + (tid >> 6);
    const int lane = tid & 63;
    const int l16 = lane & 15, lk = lane >> 4;
    const int n16 = tile / (K / 32), k32 = tile % (K / 32);
    const int n  = n16 * 16 + l16;
    const int kb = k32 * 32 + lk * 8;
    const float* s = src + (size_t)kb * N + n;
    u16x8 o;
    #pragma unroll
    for (int j = 0; j < 8; ++j) o[j] = f2b(s[(size_t)j * N]);
    *(u16x8*)(dst + (size_t)e * K * N + (size_t)tile * 512 + lane * 8) = o;
}

// ---------------- RMSNorm + router softmax + top-4 (atomic-free) ----------------
__global__ __launch_bounds__(256) void rms_router_kernel(
    const float* __restrict__ x, const float* __restrict__ rms_w,
    const float* __restrict__ cent,
    ushort* __restrict__ xnb, float* __restrict__ y, float* __restrict__ aff_out,
    int* __restrict__ tk_e, float* __restrict__ sscore)
{
    const int t   = blockIdx.x;
    const int tid = threadIdx.x;
    const int wid = tid >> 6;
    const int lane = tid & 63;

    __shared__ float xsh[DIM];
    __shared__ float red[8];
    __shared__ float logits[N_RT];

    const float4 xv = ((const float4*)(x + (size_t)t * DIM))[tid];
    float ss = xv.x*xv.x + xv.y*xv.y + xv.z*xv.z + xv.w*xv.w;
    #pragma unroll
    for (int o = 32; o > 0; o >>= 1) ss += __shfl_down(ss, o);
    if (lane == 0) red[wid] = ss;
    __syncthreads();
    if (tid == 0) {
        float s = red[0] + red[1] + red[2] + red[3];
        red[4] = rsqrtf(s * (1.0f / (float)DIM) + 1e-6f);
    }
    __syncthreads();
    const float rstd = red[4];

    const float4 wv = ((const float4*)rms_w)[tid];
    float4 nv;
    nv.x = xv.x * rstd * wv.x;
    nv.y = xv.y * rstd * wv.y;
    nv.z = xv.z * rstd * wv.z;
    nv.w = xv.w * rstd * wv.w;

    ((float4*)(y + (size_t)t * DIM))[tid] = nv;     // residual init (fp32 xn)
    ushort4 xb = make_ushort4(f2b(nv.x), f2b(nv.y), f2b(nv.z), f2b(nv.w));
    ((ushort4*)(xnb + (size_t)t * DIM))[tid] = xb;
    ((float4*)xsh)[tid] = nv;
    __syncthreads();

    #pragma unroll
    for (int ei = 0; ei < 8; ++ei) {
        const int e = wid * 8 + ei;
        const float4* c4 = (const float4*)(cent + (size_t)e * DIM);
        float acc = 0.f;
        #pragma unroll
        for (int q = 0; q < 4; ++q) {
            float4 cv = c4[lane + 64*q];
            float4 xq = ((const float4*)xsh)[lane + 64*q];
            acc += cv.x*xq.x + cv.y*xq.y + cv.z*xq.z + cv.w*xq.w;
        }
        #pragma unroll
        for (int o = 32; o > 0; o >>= 1) acc += __shfl_down(acc, o);
        if (lane == 0) logits[e] = acc;
    }
    __syncthreads();

    if (wid == 0) {
        float v = (lane < N_RT) ? logits[lane] : -INFINITY;
        float m = v;
        #pragma unroll
        for (int o = 32; o > 0; o >>= 1) m = fmaxf(m, __shfl_xor(m, o));
        float p = (lane < N_RT) ? expf(v - m) : 0.f;
        float s = p;
        #pragma unroll
        for (int o = 32; o > 0; o >>= 1) s += __shfl_xor(s, o);
        const float a = p / s;
        if (lane < N_RT) aff_out[(size_t)t * N_RT + lane] = a;
        if (lane < N_SH) sscore[(size_t)t * NSLOT + lane] = 1.f;

        float vv = (lane < N_RT) ? a : -1.f;
        #pragma unroll
        for (int it = 0; it < TOPK; ++it) {
            float mx = vv;
            #pragma unroll
            for (int o = 32; o > 0; o >>= 1) mx = fmaxf(mx, __shfl_xor(mx, o));
            unsigned long long msk = __ballot(vv == mx);
            int sel = __ffsll((long long)msk) - 1;
            sel = (sel < 0) ? 0 : (sel & (N_RT - 1));
            if (lane == 0) {
                tk_e[(size_t)t * TOPK + it] = sel;
                sscore[(size_t)t * NSLOT + 2 + it] = mx;
            }
            if (lane == sel) vv = -1.f;
        }
    }
}

// ---- scatter: block e compacts (token,slot) entries where tk_e == e ----
// 1 wave per block; deterministic (no atomics). entry i encodes (t<<2)|it.
__global__ __launch_bounds__(64) void scatter_kernel(
    const int* __restrict__ tk_e, int* __restrict__ counts, int* __restrict__ lists)
{
    const int e    = blockIdx.x;
    const int lane = threadIdx.x;
    const unsigned long long lt = (1ull << lane) - 1ull;   // lanes strictly below
    int base = 0;
    int* lst = lists + (size_t)e * T_TOK;
    for (int c = 0; c < T_TOK * TOPK; c += 256) {
        const int4 v = *(const int4*)(tk_e + c + lane * 4);
        const bool p0 = (v.x == e), p1 = (v.y == e), p2 = (v.z == e), p3 = (v.w == e);
        const unsigned long long m0 = __ballot(p0);
        const unsigned long long m1 = __ballot(p1);
        const unsigned long long m2 = __ballot(p2);
        const unsigned long long m3 = __ballot(p3);
        const int c0 = __popcll(m0), c1 = __popcll(m1), c2 = __popcll(m2);
        if (p0) lst[base + __popcll(m0 & lt)] = c + lane * 4 + 0;
        if (p1) lst[base + c0 + __popcll(m1 & lt)] = c + lane * 4 + 1;
        if (p2) lst[base + c0 + c1 + __popcll(m2 & lt)] = c + lane * 4 + 2;
        if (p3) lst[base + c0 + c1 + c2 + __popcll(m3 & lt)] = c + lane * 4 + 3;
        base += c0 + c1 + c2 + __popcll(m3);
    }
    if (lane == 0) counts[e] = base;
}

// ---- build XCD-bucketed work items: bucket b = e%8 gets expert e's tiles ----
__global__ void build_items(const int* __restrict__ counts,
                            int* __restrict__ bucket_cnt, int* __restrict__ items)
{
    const int e = threadIdx.x;           // 64 launched, 32 active
    int tiles = 0;
    if (e < N_RT) tiles = (counts[e] + TB - 1) / TB;
    const int grp = e >> 3;
    int pre = 0;
    #pragma unroll
    for (int g = 0; g < 4; ++g) {
        int tg = __shfl(tiles, (e & 7) + 8 * g, 64);
        if (g < grp) pre += tg;
    }
    if (e < N_RT) {
        for (int i = 0; i < tiles; ++i)
            items[(e & 7) * MAXPB + pre + i] = (e << 16) | i;
        if (grp == 3) bucket_cnt[e & 7] = pre + tiles;
    }
}

// ---------------- fused 2-layer expert MLP, bf16 MFMA, 32-token tiles ----------------
template<bool ATOMIC>
__global__ __launch_bounds__(256, 3) void moe_mfma(
    const ushort* __restrict__ xnb,
    const ushort* __restrict__ W1p, const ushort* __restrict__ W2p,
    const float* __restrict__ sb1, const float* __restrict__ sb2,
    const float* __restrict__ rb1, const float* __restrict__ rb2,
    const int* __restrict__ counts, const int* __restrict__ lists,
    const int* __restrict__ bucket_cnt, const int* __restrict__ items,
    const float* __restrict__ sscore,
    ushort* __restrict__ sbuf, float* __restrict__ y)
{
    const int bi  = blockIdx.x;
    const int tid = threadIdx.x;

    __shared__ int    toks[TB];
    __shared__ int    orow[TB];
    __shared__ float  tscs[TB];
    __shared__ ushort hlds[TB * HDIM];       // 16 KB, XOR-swizzled
    __shared__ ushort ostage[4 * 32 * 72];   // 18 KB, per-wave repack

    int e_full;
    const float *b1, *b2;

    if (bi < 256) {                           // shared experts: 128 tiles x 2
        e_full = bi >> 7;
        const int tile = bi & 127;
        if (tid < TB) {
            const int t = tile * TB + tid;
            toks[tid] = t;
            orow[tid] = ATOMIC ? t : t * NSLOT + e_full;
            tscs[tid] = 1.f;
        }
        b1 = sb1 + e_full * HDIM;  b2 = sb2 + e_full * DIM;
    } else {                                  // routed: bucketed queue
        const int j = bi - 256;
        const int b = j & 7, pos = j >> 3;
        if (pos >= bucket_cnt[b]) return;
        const int v = items[b * MAXPB + pos];
        const int e = v >> 16, tile = v & 0xffff;
        e_full = N_SH + e;
        const int cnt = counts[e];
        if (tid < TB) {
            const int idx = tile * TB + tid;
            if (idx < cnt) {
                const int lv = lists[(size_t)e * T_TOK + idx];
                const int t = (lv >> 2) & (T_TOK - 1);     // hardened
                toks[tid] = t;
                orow[tid] = ATOMIC ? t : t * NSLOT + 2 + (lv & 3);
                tscs[tid] = ATOMIC ? sscore[(size_t)t * NSLOT + 2 + (lv & 3)] : 0.f;
            } else {
                toks[tid] = 0;
                orow[tid] = ATOMIC ? 0 : T_TOK * NSLOT;   // dummy row
                tscs[tid] = 0.f;
            }
        }
        b1 = rb1 + e * HDIM;  b2 = rb2 + e * DIM;
    }
    __syncthreads();

    const int w = tid >> 6, lane = tid & 63;
    const int l16 = lane & 15, lk = lane >> 4;

    const ushort* abase[2];
    #pragma unroll
    for (int mi = 0; mi < 2; ++mi)
        abase[mi] = xnb + (size_t)toks[mi * 16 + l16] * DIM + lk * 8;

    const ushort* W1e = W1p + (size_t)e_full * DIM * HDIM;
    const ushort* bbase[4];
    #pragma unroll
    for (int ni = 0; ni < 4; ++ni)
        bbase[ni] = W1e + (size_t)((w * 4 + ni) * 32) * 512 + lane * 8;

    f32x4 acc[2][4];
    #pragma unroll
    for (int mi = 0; mi < 2; ++mi)
        #pragma unroll
        for (int ni = 0; ni < 4; ++ni) acc[mi][ni] = (f32x4){0.f,0.f,0.f,0.f};

    // ---- phase 1: C1[32,256] = X @ W1, K=1024, 1-deep register prefetch ----
    bf16x8 ac[2], bc[4];
    #pragma unroll
    for (int mi = 0; mi < 2; ++mi) ac[mi] = *(const bf16x8*)abase[mi];
    #pragma unroll
    for (int ni = 0; ni < 4; ++ni) bc[ni] = *(const bf16x8*)bbase[ni];

    #pragma unroll
    for (int k32 = 0; k32 < 32; ++k32) {
        bf16x8 an[2], bn[4];
        if (k32 < 31) {
            #pragma unroll
            for (int ni = 0; ni < 4; ++ni)
                bn[ni] = *(const bf16x8*)(bbase[ni] + (size_t)(k32 + 1) * 512);
            #pragma unroll
            for (int mi = 0; mi < 2; ++mi)
                an[mi] = *(const bf16x8*)(abase[mi] + (k32 + 1) * 32);
        }
        #pragma unroll
        for (int ni = 0; ni < 4; ++ni)
            #pragma unroll
            for (int mi = 0; mi < 2; ++mi)
                acc[mi][ni] = __builtin_amdgcn_mfma_f32_16x16x32_bf16(ac[mi], bc[ni], acc[mi][ni], 0, 0, 0);
        if (k32 < 31) {
            #pragma unroll
            for (int ni = 0; ni < 4; ++ni) bc[ni] = bn[ni];
            #pragma unroll
            for (int mi = 0; mi < 2; ++mi) ac[mi] = an[mi];
        }
    }

    // h = bf16(C1 + b1) -> swizzled LDS
    #pragma unroll
    for (int ni = 0; ni < 4; ++ni) {
        const int n = w * 64 + ni * 16 + l16;
        const float bv = b1[n];
        #pragma unroll
        for (int mi = 0; mi < 2; ++mi) {
            #pragma unroll
            for (int r = 0; r < 4; ++r) {
                const int m = mi * 16 + lk * 4 + r;
                const int byte = (m * (HDIM * 2) + n * 2) ^ ((m & 7) << 4);
                *(ushort*)((char*)hlds + byte) = f2b(acc[mi][ni][r] + bv);
            }
        }
    }
    __syncthreads();

    // ---- phase 2: C2[32,1024] = h @ W2, K=256, 4 column chunks ----
    const ushort* W2e = W2p + (size_t)e_full * HDIM * DIM;
    for (int jc = 0; jc < 4; ++jc) {
        f32x4 acc2[2][4];
        #pragma unroll
        for (int mi = 0; mi < 2; ++mi)
            #pragma unroll
            for (int ni = 0; ni < 4; ++ni) acc2[mi][ni] = (f32x4){0.f,0.f,0.f,0.f};

        const ushort* b2base[4];
        #pragma unroll
        for (int ni = 0; ni < 4; ++ni)
            b2base[ni] = W2e + (size_t)((jc * 16 + w * 4 + ni) * 8) * 512 + lane * 8;

        bf16x8 bc2[4];
        #pragma unroll
        for (int ni = 0; ni < 4; ++ni) bc2[ni] = *(const bf16x8*)b2base[ni];

        #pragma unroll
        for (int k32 = 0; k32 < 8; ++k32) {
            bf16x8 a2[2];
            #pragma unroll
            for (int mi = 0; mi < 2; ++mi) {
                const int m = mi * 16 + l16;
                const int byte = (m * (HDIM * 2) + (k32 * 32 + lk * 8) * 2) ^ ((m & 7) << 4);
                a2[mi] = *(const bf16x8*)((const char*)hlds + byte);
            }
            bf16x8 bn2[4];
            if (k32 < 7) {
                #pragma unroll
                for (int ni = 0; ni < 4; ++ni)
                    bn2[ni] = *(const bf16x8*)(b2base[ni] + (size_t)(k32 + 1) * 512);
            }
            #pragma unroll
            for (int ni = 0; ni < 4; ++ni)
                #pragma unroll
                for (int mi = 0; mi < 2; ++mi)
                    acc2[mi][ni] = __builtin_amdgcn_mfma_f32_16x16x32_bf16(a2[mi], bc2[ni], acc2[mi][ni], 0, 0, 0);
            if (k32 < 7) {
                #pragma unroll
                for (int ni = 0; ni < 4; ++ni) bc2[ni] = bn2[ni];
            }
        }

        if (ATOMIC) {
            #pragma unroll
            for (int ni = 0; ni < 4; ++ni) {
                const int n = jc * 256 + w * 64 + ni * 16 + l16;
                const float bv = b2[n];
                #pragma unroll
                for (int mi = 0; mi < 2; ++mi)
                    #pragma unroll
                    for (int r = 0; r < 4; ++r) {
                        const int m = mi * 16 + lk * 4 + r;
                        const float val = gelu_tanh(acc2[mi][ni][r] + bv) * tscs[m];
                        atomicAdd(&y[(size_t)orow[m] * DIM + n], val);
                    }
            }
        } else {
            // repack via per-wave LDS -> coalesced ushort8 stores (pre-gelu, pre-score)
            ushort* os = ostage + w * (32 * 72);
            asm volatile("s_waitcnt lgkmcnt(0)" ::: "memory");
            #pragma unroll
            for (int ni = 0; ni < 4; ++ni) {
                const float bv = b2[jc * 256 + w * 64 + ni * 16 + l16];
                #pragma unroll
                for (int mi = 0; mi < 2; ++mi)
                    #pragma unroll
                    for (int r = 0; r < 4; ++r) {
                        const int m = mi * 16 + lk * 4 + r;
                        os[m * 72 + ni * 16 + l16] = f2b(acc2[mi][ni][r] + bv);
                    }
            }
            asm volatile("s_waitcnt lgkmcnt(0)" ::: "memory");
            #pragma unroll
            for (int rr = 0; rr < 4; ++rr) {
                const int m  = rr * 8 + (lane >> 3);
                const int nl = (lane & 7) * 8;
                u16x8 vv = *(const u16x8*)(os + m * 72 + nl);
                *(u16x8*)(sbuf + (size_t)orow[m] * DIM + jc * 256 + w * 64 + nl) = vv;
            }
        }
    }
}

// ---------------- gather: y = xn + sum_s gelu(slot)*score ----------------
__global__ __launch_bounds__(256) void gather_kernel(
    const ushort* __restrict__ sbuf, const float* __restrict__ sscore,
    float* __restrict__ y)
{
    const int idx = blockIdx.x * 256 + threadIdx.x;   // over T*DIM/4
    const int t = idx >> 8;
    const int d = (idx & 255) * 4;
    float4 a = ((float4*)y)[idx];
    #pragma unroll
    for (int s = 0; s < NSLOT; ++s) {
        const float sc = sscore[(size_t)t * NSLOT + s];
        const ushort4 u = *(const ushort4*)(sbuf + ((size_t)t * NSLOT + s) * DIM + d);
        a.x += gelu_tanh(b2f(u.x)) * sc;
        a.y += gelu_tanh(b2f(u.y)) * sc;
        a.z += gelu_tanh(b2f(u.z)) * sc;
        a.w += gelu_tanh(b2f(u.w)) * sc;
    }
    ((float4*)y)[idx] = a;
}

extern "C" void kernel_launch(void* const* d_in, const int* in_sizes, int n_in,
                              void* d_out, int out_size, void* d_ws, size_t ws_size,
                              hipStream_t stream) {
    const float* x      = (const float*)d_in[0];
    const float* rms_w  = (const float*)d_in[1];
    const float* cent   = (const float*)d_in[2];
    const float* sW1    = (const float*)d_in[3];
    const float* sb1    = (const float*)d_in[4];
    const float* sW2    = (const float*)d_in[5];
    const float* sb2    = (const float*)d_in[6];
    const float* rW1    = (const float*)d_in[7];
    const float* rb1    = (const float*)d_in[8];
    const float* rW2    = (const float*)d_in[9];
    const float* rb2    = (const float*)d_in[10];

    float* y_out   = (float*)d_out;
    float* aff_out = (float*)d_out + (size_t)T_TOK * DIM;

    char* p = (char*)d_ws;
    size_t off = 0;
    auto take = [&](size_t b) {
        char* r = p + off;
        off += (b + 255) & ~(size_t)255;
        return r;
    };
    ushort* xnb    = (ushort*)take((size_t)T_TOK * DIM * 2);
    ushort* W1p    = (ushort*)take((size_t)N_E * DIM * HDIM * 2);
    ushort* W2p    = (ushort*)take((size_t)N_E * HDIM * DIM * 2);
    int*    counts = (int*)take(N_RT * sizeof(int));
    int*    lists  = (int*)take((size_t)N_RT * T_TOK * 4);
    float*  sscore = (float*)take((size_t)T_TOK * NSLOT * 4);
    int*    tk_e   = (int*)take((size_t)T_TOK * TOPK * 4);
    int*    bcnt   = (int*)take(8 * sizeof(int));
    int*    items  = (int*)take((size_t)8 * MAXPB * 4);
    ushort* sbuf   = (ushort*)take(((size_t)T_TOK * NSLOT + 32) * DIM * 2);
    const bool slot_ok = (off <= ws_size);

    pack_weights<DIM,  HDIM><<<dim3(128, N_E), dim3(256), 0, stream>>>(sW1, rW1, W1p);
    pack_weights<HDIM, DIM ><<<dim3(128, N_E), dim3(256), 0, stream>>>(sW2, rW2, W2p);

    rms_router_kernel<<<dim3(T_TOK), dim3(256), 0, stream>>>(
        x, rms_w, cent, xnb, y_out, aff_out, tk_e, sscore);

    scatter_kernel<<<dim3(N_RT), dim3(64), 0, stream>>>(tk_e, counts, lists);
    build_items<<<dim3(1), dim3(64), 0, stream>>>(counts, bcnt, items);

    const int grid = 256 + 8 * MAXPB;
    if (slot_ok) {
        moe_mfma<false><<<dim3(grid), dim3(256), 0, stream>>>(
            xnb, W1p, W2p, sb1, sb2, rb1, rb2, counts, lists, bcnt, items,
            sscore, sbuf, y_out);
        gather_kernel<<<dim3((T_TOK * DIM / 4) / 256), dim3(256), 0, stream>>>(
            sbuf, sscore, y_out);
    } else {
        moe_mfma<true><<<dim3(grid), dim3(256), 0, stream>>>(
            xnb, W1p, W2p, sb1, sb2, rb1, rb2, counts, lists, bcnt, items,
            sscore, sbuf, y_out);
    }
}

// Round 6
// 174.435 us; speedup vs baseline: 9.6893x; 1.0731x over previous
//
#include <hip/hip_runtime.h>
#include <hip/hip_bf16.h>
#include <math.h>

#define T_TOK 4096
#define DIM   1024
#define HDIM  256
#define N_SH  2
#define N_RT  32
#define N_E   34
#define TOPK  4
#define TB    64
#define MAXPB 260
#define NSLOT 6
#define OSW   34          // ostage row stride (32 cols + 2 pad)

typedef short bf16x8 __attribute__((ext_vector_type(8)));
typedef float f32x4  __attribute__((ext_vector_type(4)));
typedef unsigned short u16x8 __attribute__((ext_vector_type(8)));

__device__ __forceinline__ ushort f2b(float v) {
    __hip_bfloat16 h = __float2bfloat16(v);
    return *reinterpret_cast<const ushort*>(&h);
}
__device__ __forceinline__ float b2f(ushort u) {
    unsigned int x = ((unsigned int)u) << 16;
    return __uint_as_float(x);
}
__device__ __forceinline__ float gelu_tanh(float x) {
    float z = 0.7978845608028654f * (x + 0.044715f * x * x * x);
    float e = __expf(2.0f * z);
    float t = 1.0f - 2.0f / (e + 1.0f);
    return 0.5f * x * (1.0f + t);
}

// ---- pack weights: src[E][K][N] fp32 -> per-MFMA-fragment bf16 tiles ----
template<int K, int N>
__global__ __launch_bounds__(256) void pack_weights(
    const float* __restrict__ srcS, const float* __restrict__ srcR,
    ushort* __restrict__ dst)
{
    const int e = blockIdx.y;
    const float* src = (e < N_SH) ? (srcS + (size_t)e * K * N)
                                  : (srcR + (size_t)(e - N_SH) * K * N);
    const int tid  = threadIdx.x;
    const int tile = blockIdx.x * 4 + (tid >> 6);
    const int lane = tid & 63;
    const int l16 = lane & 15, lk = lane >> 4;
    const int n16 = tile / (K / 32), k32 = tile % (K / 32);
    const int n  = n16 * 16 + l16;
    const int kb = k32 * 32 + lk * 8;
    const float* s = src + (size_t)kb * N + n;
    u16x8 o;
    #pragma unroll
    for (int j = 0; j < 8; ++j) o[j] = f2b(s[(size_t)j * N]);
    *(u16x8*)(dst + (size_t)e * K * N + (size_t)tile * 512 + lane * 8) = o;
}

// ---------------- RMSNorm + router softmax + top-4 (atomic-free) ----------------
__global__ __launch_bounds__(256) void rms_router_kernel(
    const float* __restrict__ x, const float* __restrict__ rms_w,
    const float* __restrict__ cent,
    ushort* __restrict__ xnb, float* __restrict__ y, float* __restrict__ aff_out,
    int* __restrict__ tk_e, float* __restrict__ sscore)
{
    const int t   = blockIdx.x;
    const int tid = threadIdx.x;
    const int wid = tid >> 6;
    const int lane = tid & 63;

    __shared__ float xsh[DIM];
    __shared__ float red[8];
    __shared__ float logits[N_RT];

    const float4 xv = ((const float4*)(x + (size_t)t * DIM))[tid];
    float ss = xv.x*xv.x + xv.y*xv.y + xv.z*xv.z + xv.w*xv.w;
    #pragma unroll
    for (int o = 32; o > 0; o >>= 1) ss += __shfl_down(ss, o);
    if (lane == 0) red[wid] = ss;
    __syncthreads();
    if (tid == 0) {
        float s = red[0] + red[1] + red[2] + red[3];
        red[4] = rsqrtf(s * (1.0f / (float)DIM) + 1e-6f);
    }
    __syncthreads();
    const float rstd = red[4];

    const float4 wv = ((const float4*)rms_w)[tid];
    float4 nv;
    nv.x = xv.x * rstd * wv.x;
    nv.y = xv.y * rstd * wv.y;
    nv.z = xv.z * rstd * wv.z;
    nv.w = xv.w * rstd * wv.w;

    ((float4*)(y + (size_t)t * DIM))[tid] = nv;     // residual init (fp32 xn)
    ushort4 xb = make_ushort4(f2b(nv.x), f2b(nv.y), f2b(nv.z), f2b(nv.w));
    ((ushort4*)(xnb + (size_t)t * DIM))[tid] = xb;
    ((float4*)xsh)[tid] = nv;
    __syncthreads();

    #pragma unroll
    for (int ei = 0; ei < 8; ++ei) {
        const int e = wid * 8 + ei;
        const float4* c4 = (const float4*)(cent + (size_t)e * DIM);
        float acc = 0.f;
        #pragma unroll
        for (int q = 0; q < 4; ++q) {
            float4 cv = c4[lane + 64*q];
            float4 xq = ((const float4*)xsh)[lane + 64*q];
            acc += cv.x*xq.x + cv.y*xq.y + cv.z*xq.z + cv.w*xq.w;
        }
        #pragma unroll
        for (int o = 32; o > 0; o >>= 1) acc += __shfl_down(acc, o);
        if (lane == 0) logits[e] = acc;
    }
    __syncthreads();

    if (wid == 0) {
        float v = (lane < N_RT) ? logits[lane] : -INFINITY;
        float m = v;
        #pragma unroll
        for (int o = 32; o > 0; o >>= 1) m = fmaxf(m, __shfl_xor(m, o));
        float p = (lane < N_RT) ? expf(v - m) : 0.f;
        float s = p;
        #pragma unroll
        for (int o = 32; o > 0; o >>= 1) s += __shfl_xor(s, o);
        const float a = p / s;
        if (lane < N_RT) aff_out[(size_t)t * N_RT + lane] = a;
        if (lane < N_SH) sscore[(size_t)t * NSLOT + lane] = 1.f;

        float vv = (lane < N_RT) ? a : -1.f;
        #pragma unroll
        for (int it = 0; it < TOPK; ++it) {
            float mx = vv;
            #pragma unroll
            for (int o = 32; o > 0; o >>= 1) mx = fmaxf(mx, __shfl_xor(mx, o));
            unsigned long long msk = __ballot(vv == mx);
            int sel = __ffsll((long long)msk) - 1;
            sel = (sel < 0) ? 0 : (sel & (N_RT - 1));
            if (lane == 0) {
                tk_e[(size_t)t * TOPK + it] = sel;
                sscore[(size_t)t * NSLOT + 2 + it] = mx;
            }
            if (lane == sel) vv = -1.f;
        }
    }
}

// ---- scatter: block e compacts (token,slot) entries where tk_e == e ----
__global__ __launch_bounds__(64) void scatter_kernel(
    const int* __restrict__ tk_e, int* __restrict__ counts, int* __restrict__ lists)
{
    const int e    = blockIdx.x;
    const int lane = threadIdx.x;
    const unsigned long long lt = (1ull << lane) - 1ull;   // lanes strictly below
    int base = 0;
    int* lst = lists + (size_t)e * T_TOK;
    for (int c = 0; c < T_TOK * TOPK; c += 256) {
        const int4 v = *(const int4*)(tk_e + c + lane * 4);
        const bool p0 = (v.x == e), p1 = (v.y == e), p2 = (v.z == e), p3 = (v.w == e);
        const unsigned long long m0 = __ballot(p0);
        const unsigned long long m1 = __ballot(p1);
        const unsigned long long m2 = __ballot(p2);
        const unsigned long long m3 = __ballot(p3);
        const int c0 = __popcll(m0), c1 = __popcll(m1), c2 = __popcll(m2);
        if (p0) lst[base + __popcll(m0 & lt)] = c + lane * 4 + 0;
        if (p1) lst[base + c0 + __popcll(m1 & lt)] = c + lane * 4 + 1;
        if (p2) lst[base + c0 + c1 + __popcll(m2 & lt)] = c + lane * 4 + 2;
        if (p3) lst[base + c0 + c1 + c2 + __popcll(m3 & lt)] = c + lane * 4 + 3;
        base += c0 + c1 + c2 + __popcll(m3);
    }
    if (lane == 0) counts[e] = base;
}

// ---- build XCD-bucketed work items: bucket b = e%8 gets expert e's tiles ----
__global__ void build_items(const int* __restrict__ counts,
                            int* __restrict__ bucket_cnt, int* __restrict__ items)
{
    const int e = threadIdx.x;           // 64 launched, 32 active
    int tiles = 0;
    if (e < N_RT) tiles = (counts[e] + TB - 1) / TB;
    const int grp = e >> 3;
    int pre = 0;
    #pragma unroll
    for (int g = 0; g < 4; ++g) {
        int tg = __shfl(tiles, (e & 7) + 8 * g, 64);
        if (g < grp) pre += tg;
    }
    if (e < N_RT) {
        for (int i = 0; i < tiles; ++i)
            items[(e & 7) * MAXPB + pre + i] = (e << 16) | i;
        if (grp == 3) bucket_cnt[e & 7] = pre + tiles;
    }
}

// ---------------- fused 2-layer expert MLP, bf16 MFMA, 64-token tiles ----------------
template<bool ATOMIC>
__global__ __launch_bounds__(256, 3) void moe_mfma(
    const ushort* __restrict__ xnb,
    const ushort* __restrict__ W1p, const ushort* __restrict__ W2p,
    const float* __restrict__ sb1, const float* __restrict__ sb2,
    const float* __restrict__ rb1, const float* __restrict__ rb2,
    const int* __restrict__ counts, const int* __restrict__ lists,
    const int* __restrict__ bucket_cnt, const int* __restrict__ items,
    const float* __restrict__ sscore,
    ushort* __restrict__ sbuf, float* __restrict__ y)
{
    const int bi  = blockIdx.x;
    const int tid = threadIdx.x;

    __shared__ int    toks[TB];
    __shared__ int    orow[TB];
    __shared__ float  tscs[TB];
    __shared__ ushort hlds[TB * HDIM];          // 32 KB, XOR-swizzled
    __shared__ ushort ostage[4 * TB * OSW];     // 17 KB, per-wave repack

    int e_full;
    const float *b1, *b2;

    if (bi < 128) {                           // shared experts: 64 tiles x 2
        e_full = bi >> 6;
        const int tile = bi & 63;
        if (tid < TB) {
            const int t = tile * TB + tid;
            toks[tid] = t;
            orow[tid] = ATOMIC ? t : t * NSLOT + e_full;
            tscs[tid] = 1.f;
        }
        b1 = sb1 + e_full * HDIM;  b2 = sb2 + e_full * DIM;
    } else {                                  // routed: bucketed queue
        const int j = bi - 128;
        const int b = j & 7, pos = j >> 3;
        if (pos >= bucket_cnt[b]) return;
        const int v = items[b * MAXPB + pos];
        const int e = v >> 16, tile = v & 0xffff;
        e_full = N_SH + e;
        const int cnt = counts[e];
        if (tid < TB) {
            const int idx = tile * TB + tid;
            if (idx < cnt) {
                const int lv = lists[(size_t)e * T_TOK + idx];
                const int t = (lv >> 2) & (T_TOK - 1);     // hardened
                toks[tid] = t;
                orow[tid] = ATOMIC ? t : t * NSLOT + 2 + (lv & 3);
                tscs[tid] = ATOMIC ? sscore[(size_t)t * NSLOT + 2 + (lv & 3)] : 0.f;
            } else {
                toks[tid] = 0;
                orow[tid] = ATOMIC ? 0 : T_TOK * NSLOT;   // dummy row
                tscs[tid] = 0.f;
            }
        }
        b1 = rb1 + e * HDIM;  b2 = rb2 + e * DIM;
    }
    __syncthreads();

    const int w = tid >> 6, lane = tid & 63;
    const int l16 = lane & 15, lk = lane >> 4;

    const ushort* abase[4];
    #pragma unroll
    for (int mi = 0; mi < 4; ++mi)
        abase[mi] = xnb + (size_t)toks[mi * 16 + l16] * DIM + lk * 8;

    const ushort* W1e = W1p + (size_t)e_full * DIM * HDIM;
    const ushort* bbase[4];
    #pragma unroll
    for (int ni = 0; ni < 4; ++ni)
        bbase[ni] = W1e + (size_t)((w * 4 + ni) * 32) * 512 + lane * 8;

    f32x4 acc[4][4];
    #pragma unroll
    for (int mi = 0; mi < 4; ++mi)
        #pragma unroll
        for (int ni = 0; ni < 4; ++ni) acc[mi][ni] = (f32x4){0.f,0.f,0.f,0.f};

    // ---- phase 1: C1[64,256] = X @ W1, K=1024, 1-deep register prefetch ----
    bf16x8 ac[4], bc[4];
    #pragma unroll
    for (int mi = 0; mi < 4; ++mi) ac[mi] = *(const bf16x8*)abase[mi];
    #pragma unroll
    for (int ni = 0; ni < 4; ++ni) bc[ni] = *(const bf16x8*)bbase[ni];

    #pragma unroll
    for (int k32 = 0; k32 < 32; ++k32) {
        bf16x8 an[4], bn[4];
        if (k32 < 31) {
            #pragma unroll
            for (int ni = 0; ni < 4; ++ni)
                bn[ni] = *(const bf16x8*)(bbase[ni] + (size_t)(k32 + 1) * 512);
            #pragma unroll
            for (int mi = 0; mi < 4; ++mi)
                an[mi] = *(const bf16x8*)(abase[mi] + (k32 + 1) * 32);
        }
        #pragma unroll
        for (int ni = 0; ni < 4; ++ni)
            #pragma unroll
            for (int mi = 0; mi < 4; ++mi)
                acc[mi][ni] = __builtin_amdgcn_mfma_f32_16x16x32_bf16(ac[mi], bc[ni], acc[mi][ni], 0, 0, 0);
        if (k32 < 31) {
            #pragma unroll
            for (int ni = 0; ni < 4; ++ni) bc[ni] = bn[ni];
            #pragma unroll
            for (int mi = 0; mi < 4; ++mi) ac[mi] = an[mi];
        }
    }

    // h = bf16(C1 + b1) -> swizzled LDS
    #pragma unroll
    for (int ni = 0; ni < 4; ++ni) {
        const int n = w * 64 + ni * 16 + l16;
        const float bv = b1[n];
        #pragma unroll
        for (int mi = 0; mi < 4; ++mi) {
            #pragma unroll
            for (int r = 0; r < 4; ++r) {
                const int m = mi * 16 + lk * 4 + r;
                const int byte = (m * (HDIM * 2) + n * 2) ^ ((m & 7) << 4);
                *(ushort*)((char*)hlds + byte) = f2b(acc[mi][ni][r] + bv);
            }
        }
    }
    __syncthreads();

    // ---- phase 2: C2[64,1024] = h @ W2, K=256, 4 column chunks ----
    const ushort* W2e = W2p + (size_t)e_full * HDIM * DIM;
    for (int jc = 0; jc < 4; ++jc) {
        f32x4 acc2[4][4];
        #pragma unroll
        for (int mi = 0; mi < 4; ++mi)
            #pragma unroll
            for (int ni = 0; ni < 4; ++ni) acc2[mi][ni] = (f32x4){0.f,0.f,0.f,0.f};

        const ushort* b2base[4];
        #pragma unroll
        for (int ni = 0; ni < 4; ++ni)
            b2base[ni] = W2e + (size_t)((jc * 16 + w * 4 + ni) * 8) * 512 + lane * 8;

        bf16x8 bc2[4];
        #pragma unroll
        for (int ni = 0; ni < 4; ++ni) bc2[ni] = *(const bf16x8*)b2base[ni];

        #pragma unroll
        for (int k32 = 0; k32 < 8; ++k32) {
            bf16x8 a2[4];
            #pragma unroll
            for (int mi = 0; mi < 4; ++mi) {
                const int m = mi * 16 + l16;
                const int byte = (m * (HDIM * 2) + (k32 * 32 + lk * 8) * 2) ^ ((m & 7) << 4);
                a2[mi] = *(const bf16x8*)((const char*)hlds + byte);
            }
            bf16x8 bn2[4];
            if (k32 < 7) {
                #pragma unroll
                for (int ni = 0; ni < 4; ++ni)
                    bn2[ni] = *(const bf16x8*)(b2base[ni] + (size_t)(k32 + 1) * 512);
            }
            #pragma unroll
            for (int ni = 0; ni < 4; ++ni)
                #pragma unroll
                for (int mi = 0; mi < 4; ++mi)
                    acc2[mi][ni] = __builtin_amdgcn_mfma_f32_16x16x32_bf16(a2[mi], bc2[ni], acc2[mi][ni], 0, 0, 0);
            if (k32 < 7) {
                #pragma unroll
                for (int ni = 0; ni < 4; ++ni) bc2[ni] = bn2[ni];
            }
        }

        if (ATOMIC) {
            #pragma unroll
            for (int ni = 0; ni < 4; ++ni) {
                const int n = jc * 256 + w * 64 + ni * 16 + l16;
                const float bv = b2[n];
                #pragma unroll
                for (int mi = 0; mi < 4; ++mi)
                    #pragma unroll
                    for (int r = 0; r < 4; ++r) {
                        const int m = mi * 16 + lk * 4 + r;
                        const float val = gelu_tanh(acc2[mi][ni][r] + bv) * tscs[m];
                        atomicAdd(&y[(size_t)orow[m] * DIM + n], val);
                    }
            }
        } else {
            // per-wave LDS repack (2 ni at a time) -> coalesced 64B-per-row stores
            ushort* os = ostage + w * (TB * OSW);
            #pragma unroll
            for (int p = 0; p < 2; ++p) {
                asm volatile("s_waitcnt lgkmcnt(0)" ::: "memory");
                #pragma unroll
                for (int q = 0; q < 2; ++q) {
                    const int ni = p * 2 + q;
                    const float bv = b2[jc * 256 + w * 64 + ni * 16 + l16];
                    #pragma unroll
                    for (int mi = 0; mi < 4; ++mi)
                        #pragma unroll
                        for (int r = 0; r < 4; ++r) {
                            const int m = mi * 16 + lk * 4 + r;
                            os[m * OSW + q * 16 + l16] = f2b(acc2[mi][ni][r] + bv);
                        }
                }
                asm volatile("s_waitcnt lgkmcnt(0)" ::: "memory");
                #pragma unroll
                for (int rr = 0; rr < 4; ++rr) {
                    const int m  = rr * 16 + (lane >> 2);
                    const int nl = (lane & 3) * 8;
                    u16x8 vv = *(const u16x8*)(os + m * OSW + nl);
                    *(u16x8*)(sbuf + (size_t)orow[m] * DIM + jc * 256 + w * 64 + p * 32 + nl) = vv;
                }
            }
        }
    }
}

// ---------------- gather: y = xn + sum_s gelu(slot)*score ----------------
__global__ __launch_bounds__(256) void gather_kernel(
    const ushort* __restrict__ sbuf, const float* __restrict__ sscore,
    float* __restrict__ y)
{
    const int idx = blockIdx.x * 256 + threadIdx.x;   // over T*DIM/4
    const int t = idx >> 8;
    const int d = (idx & 255) * 4;
    float4 a = ((float4*)y)[idx];
    #pragma unroll
    for (int s = 0; s < NSLOT; ++s) {
        const float sc = sscore[(size_t)t * NSLOT + s];
        const ushort4 u = *(const ushort4*)(sbuf + ((size_t)t * NSLOT + s) * DIM + d);
        a.x += gelu_tanh(b2f(u.x)) * sc;
        a.y += gelu_tanh(b2f(u.y)) * sc;
        a.z += gelu_tanh(b2f(u.z)) * sc;
        a.w += gelu_tanh(b2f(u.w)) * sc;
    }
    ((float4*)y)[idx] = a;
}

extern "C" void kernel_launch(void* const* d_in, const int* in_sizes, int n_in,
                              void* d_out, int out_size, void* d_ws, size_t ws_size,
                              hipStream_t stream) {
    const float* x      = (const float*)d_in[0];
    const float* rms_w  = (const float*)d_in[1];
    const float* cent   = (const float*)d_in[2];
    const float* sW1    = (const float*)d_in[3];
    const float* sb1    = (const float*)d_in[4];
    const float* sW2    = (const float*)d_in[5];
    const float* sb2    = (const float*)d_in[6];
    const float* rW1    = (const float*)d_in[7];
    const float* rb1    = (const float*)d_in[8];
    const float* rW2    = (const float*)d_in[9];
    const float* rb2    = (const float*)d_in[10];

    float* y_out   = (float*)d_out;
    float* aff_out = (float*)d_out + (size_t)T_TOK * DIM;

    char* p = (char*)d_ws;
    size_t off = 0;
    auto take = [&](size_t b) {
        char* r = p + off;
        off += (b + 255) & ~(size_t)255;
        return r;
    };
    ushort* xnb    = (ushort*)take((size_t)T_TOK * DIM * 2);
    ushort* W1p    = (ushort*)take((size_t)N_E * DIM * HDIM * 2);
    ushort* W2p    = (ushort*)take((size_t)N_E * HDIM * DIM * 2);
    int*    counts = (int*)take(N_RT * sizeof(int));
    int*    lists  = (int*)take((size_t)N_RT * T_TOK * 4);
    float*  sscore = (float*)take((size_t)T_TOK * NSLOT * 4);
    int*    tk_e   = (int*)take((size_t)T_TOK * TOPK * 4);
    int*    bcnt   = (int*)take(8 * sizeof(int));
    int*    items  = (int*)take((size_t)8 * MAXPB * 4);
    ushort* sbuf   = (ushort*)take(((size_t)T_TOK * NSLOT + TB) * DIM * 2);
    const bool slot_ok = (off <= ws_size);

    pack_weights<DIM,  HDIM><<<dim3(128, N_E), dim3(256), 0, stream>>>(sW1, rW1, W1p);
    pack_weights<HDIM, DIM ><<<dim3(128, N_E), dim3(256), 0, stream>>>(sW2, rW2, W2p);

    rms_router_kernel<<<dim3(T_TOK), dim3(256), 0, stream>>>(
        x, rms_w, cent, xnb, y_out, aff_out, tk_e, sscore);

    scatter_kernel<<<dim3(N_RT), dim3(64), 0, stream>>>(tk_e, counts, lists);
    build_items<<<dim3(1), dim3(64), 0, stream>>>(counts, bcnt, items);

    const int grid = 128 + 8 * MAXPB;
    if (slot_ok) {
        moe_mfma<false><<<dim3(grid), dim3(256), 0, stream>>>(
            xnb, W1p, W2p, sb1, sb2, rb1, rb2, counts, lists, bcnt, items,
            sscore, sbuf, y_out);
        gather_kernel<<<dim3((T_TOK * DIM / 4) / 256), dim3(256), 0, stream>>>(
            sbuf, sscore, y_out);
    } else {
        moe_mfma<true><<<dim3(grid), dim3(256), 0, stream>>>(
            xnb, W1p, W2p, sb1, sb2, rb1, rb2, counts, lists, bcnt, items,
            sscore, sbuf, y_out);
    }
}